// Round 1
// baseline (165.541 us; speedup 1.0000x reference)
//
#include <hip/hip_runtime.h>
#include <hip/hip_cooperative_groups.h>
#include <math.h>

namespace cg = cooperative_groups;

namespace {

constexpr int K_ = 4;
constexpr int T_ = 1024;
constexpr int B_ = 2;
constexpr int D_ = 256;
constexpr int NSEQ = B_ * D_;        // 512 independent (b,d) sequences

constexpr int CH = 128;              // fine time chunks
constexpr int L_ = T_ / CH;          // 8 steps per chunk
constexpr int LOG_CH = 7;

// ---------------------------------------------------------------------------
// Compile-time-foldable constants: Abar, Bbar (bilinear LegT, N=4, theta=200)
// exactly as the reference builds them, plus AP[s] = Abar^(L*2^s), s=0..6.
// ---------------------------------------------------------------------------
__device__ __forceinline__ void base_consts(float Af[4][4], float Bf[4]) {
    const double dt = 1.0 / 200.0;
    double P[4], A[4][4];
#pragma unroll
    for (int n = 0; n < 4; ++n) P[n] = sqrt(2.0 * n + 1.0);
#pragma unroll
    for (int n = 0; n < 4; ++n)
#pragma unroll
        for (int k = 0; k < 4; ++k) {
            double s = (n >= k) ? 1.0 : (((k - n) & 1) ? -1.0 : 1.0);
            A[n][k] = -P[n] * P[k] * s;
        }
    double aug[4][9];
#pragma unroll
    for (int r = 0; r < 4; ++r) {
#pragma unroll
        for (int c = 0; c < 4; ++c) {
            double idc = (r == c) ? 1.0 : 0.0;
            aug[r][c]     = idc - 0.5 * dt * A[r][c];
            aug[r][4 + c] = idc + 0.5 * dt * A[r][c];
        }
        aug[r][8] = P[r] * dt;
    }
#pragma unroll
    for (int p = 0; p < 4; ++p) {
        double pinv = 1.0 / aug[p][p];
#pragma unroll
        for (int c = 0; c < 9; ++c) aug[p][c] *= pinv;
#pragma unroll
        for (int r = 0; r < 4; ++r) {
            if (r == p) continue;
            double f = aug[r][p];
#pragma unroll
            for (int c = 0; c < 9; ++c) aug[r][c] -= f * aug[p][c];
        }
    }
#pragma unroll
    for (int r = 0; r < 4; ++r) {
#pragma unroll
        for (int c = 0; c < 4; ++c) Af[r][c] = (float)aug[r][4 + c];
        Bf[r] = (float)aug[r][8];
    }
}

__device__ __forceinline__ void matsq(const float X[4][4], float Y[4][4]) {
#pragma unroll
    for (int r = 0; r < 4; ++r)
#pragma unroll
        for (int c = 0; c < 4; ++c) {
            float acc = 0.f;
#pragma unroll
            for (int k = 0; k < 4; ++k) acc = fmaf(X[r][k], X[k][c], acc);
            Y[r][c] = acc;
        }
}

// AP[s] = Abar^(8 * 2^s), s = 0..LOG_CH-1
__device__ __forceinline__ void scan_consts(float AP[LOG_CH][4][4]) {
    float Af[4][4], Bf[4];
    base_consts(Af, Bf);
    float X[4][4], Y[4][4];
    matsq(Af, X);      // A^2
    matsq(X, Y);       // A^4
    matsq(Y, X);       // A^8
#pragma unroll
    for (int s = 0; s < LOG_CH; ++s) {
#pragma unroll
        for (int r = 0; r < 4; ++r)
#pragma unroll
            for (int c = 0; c < 4; ++c) AP[s][r][c] = X[r][c];
        matsq(X, Y);
#pragma unroll
        for (int r = 0; r < 4; ++r)
#pragma unroll
            for (int c = 0; c < 4; ++c) X[r][c] = Y[r][c];
    }
}

// ===========================================================================
// Fused cooperative kernel: all three phases, grid = 256 blocks x 256 thr
// (exactly 1 block/CU -> cooperative co-residency trivially satisfied).
//
//  phase 1: block (b,c) computes chunk-local end states for all 256 d,
//           staging the 8x256 h-tile into LDS (h read from HBM ONCE).
//  phase 2: block = seq-pair, Kogge-Stone scan over 128 chunks (as k1b).
//  phase 3: block (b,c) emits 8 timesteps reading h from LDS (same block
//           mapping as phase 1, same thread owns same d -> no sync needed
//           for hbuf).
// ===========================================================================
__global__ __launch_bounds__(256) void fused_all(
    const float* __restrict__ h, const float* __restrict__ M,
    float* __restrict__ ws_y, float* __restrict__ ws_init,
    float* __restrict__ out)
{
    const int tid = threadIdx.x;
    const int bid = blockIdx.x;

    __shared__ float  hbuf[L_][D_];   // 8 KiB: h tile, lives phase1 -> phase3
    __shared__ float4 lds[CH * 2];    // 4 KiB: scan exchange buffer

    // ---------------- phase 1: chunk-local end states ----------------
    {
        const int d = tid;
        const int c = bid & (CH - 1);
        const int b = bid >> LOG_CH;
        const float* hp = h + ((size_t)(b * T_ + c * L_)) * D_ + d;
        float y0 = 0.f, y1 = 0.f, y2 = 0.f, y3 = 0.f;
#pragma unroll
        for (int i = 0; i < L_; ++i) {
            float hv = hp[i * D_];            // 1 KiB coalesced per instr
            hbuf[i][d] = hv;                  // stash for phase 3
            const float* mr = M + (L_ - 1 - i) * K_;
            y0 = fmaf(mr[0], hv, y0);
            y1 = fmaf(mr[1], hv, y1);
            y2 = fmaf(mr[2], hv, y2);
            y3 = fmaf(mr[3], hv, y3);
        }
        ((float4*)ws_y)[(size_t)c * NSEQ + b * D_ + d] =
            make_float4(y0, y1, y2, y3);      // 4 KiB contiguous per block
    }

    __threadfence();
    cg::this_grid().sync();

    // ---------------- phase 2: Kogge-Stone scan over chunks ----------------
    {
        const int sp  = tid & 1;
        const int c   = tid >> 1;             // 0..127
        const int seq = bid * 2 + sp;

        float AP[LOG_CH][4][4];
        scan_consts(AP);

        float4 v = ((const float4*)ws_y)[(size_t)c * NSEQ + seq];
#pragma unroll
        for (int s = 0; s < LOG_CH; ++s) {
            const int off = 1 << s;
            lds[tid] = v;
            __syncthreads();
            if (c >= off) {
                float4 p = lds[tid - off * 2];
                v.x = fmaf(AP[s][0][0], p.x, fmaf(AP[s][0][1], p.y, fmaf(AP[s][0][2], p.z, fmaf(AP[s][0][3], p.w, v.x))));
                v.y = fmaf(AP[s][1][0], p.x, fmaf(AP[s][1][1], p.y, fmaf(AP[s][1][2], p.z, fmaf(AP[s][1][3], p.w, v.y))));
                v.z = fmaf(AP[s][2][0], p.x, fmaf(AP[s][2][1], p.y, fmaf(AP[s][2][2], p.z, fmaf(AP[s][2][3], p.w, v.z))));
                v.w = fmaf(AP[s][3][0], p.x, fmaf(AP[s][3][1], p.y, fmaf(AP[s][3][2], p.z, fmaf(AP[s][3][3], p.w, v.w))));
            }
            __syncthreads();
        }
        // v = inclusive state after chunk c; init[c+1] = v, init[0] = 0
        float4* ip = (float4*)ws_init;
        if (c < CH - 1) ip[(size_t)(c + 1) * NSEQ + seq] = v;
        if (c == 0)     ip[seq] = make_float4(0.f, 0.f, 0.f, 0.f);
    }

    __threadfence();
    cg::this_grid().sync();

    // ---------------- phase 3: emit (h comes from LDS) ----------------
    {
        const int d = tid;
        const int c = bid & (CH - 1);
        const int b = bid >> LOG_CH;

        float Af[4][4], Bf[4];
        base_consts(Af, Bf);

        float4 xi = ((const float4*)ws_init)[(size_t)c * NSEQ + b * D_ + d];
        float x0 = xi.x, x1 = xi.y, x2 = xi.z, x3 = xi.w;

        float* op = out + ((size_t)(b * T_ + c * L_)) * K_ * D_ + d;
#pragma unroll
        for (int i = 0; i < L_; ++i) {
            float hv = hbuf[i][d];            // same thread wrote it: no sync
            float n0 = fmaf(Af[0][0], x0, fmaf(Af[0][1], x1, fmaf(Af[0][2], x2, fmaf(Af[0][3], x3, Bf[0] * hv))));
            float n1 = fmaf(Af[1][0], x0, fmaf(Af[1][1], x1, fmaf(Af[1][2], x2, fmaf(Af[1][3], x3, Bf[1] * hv))));
            float n2 = fmaf(Af[2][0], x0, fmaf(Af[2][1], x1, fmaf(Af[2][2], x2, fmaf(Af[2][3], x3, Bf[2] * hv))));
            float n3 = fmaf(Af[3][0], x0, fmaf(Af[3][1], x1, fmaf(Af[3][2], x2, fmaf(Af[3][3], x3, Bf[3] * hv))));
            x0 = n0; x1 = n1; x2 = n2; x3 = n3;
            op[0 * D_] = x0; op[1 * D_] = x1; op[2 * D_] = x2; op[3 * D_] = x3;
            op += K_ * D_;
        }
    }
}

// ===========================================================================
// Fallback path (original 3-kernel pipeline) in case cooperative launch
// is rejected under graph capture.
// ===========================================================================
__global__ __launch_bounds__(256) void k1a_chunk_states(
    const float* __restrict__ h, const float* __restrict__ M,
    float* __restrict__ ws_y)
{
    const int dlane = threadIdx.x & 63;
    const int csub  = threadIdx.x >> 6;
    const int sg    = blockIdx.x & 7;
    const int cg    = blockIdx.x >> 3;
    const int seq = sg * 64 + dlane;
    const int b = seq >> 8, d = seq & (D_ - 1);
    const int c = cg * 4 + csub;

    const float* hp = h + ((size_t)(b * T_ + c * L_)) * D_ + d;
    float y0 = 0.f, y1 = 0.f, y2 = 0.f, y3 = 0.f;
#pragma unroll
    for (int i = 0; i < L_; ++i) {
        float hv = hp[i * D_];
        const float* mr = M + (L_ - 1 - i) * K_;
        y0 = fmaf(mr[0], hv, y0);
        y1 = fmaf(mr[1], hv, y1);
        y2 = fmaf(mr[2], hv, y2);
        y3 = fmaf(mr[3], hv, y3);
    }
    float4* wp = (float4*)ws_y + (size_t)c * NSEQ + seq;
    *wp = make_float4(y0, y1, y2, y3);
}

__global__ __launch_bounds__(256) void k1b_scan(
    const float* __restrict__ ws_y, float* __restrict__ ws_init)
{
    const int sp = threadIdx.x & 1;
    const int c  = threadIdx.x >> 1;
    const int seq = blockIdx.x * 2 + sp;

    float AP[LOG_CH][4][4];
    scan_consts(AP);

    float4 v = ((const float4*)ws_y)[(size_t)c * NSEQ + seq];

    __shared__ float4 lds[CH * 2];
#pragma unroll
    for (int s = 0; s < LOG_CH; ++s) {
        const int off = 1 << s;
        lds[threadIdx.x] = v;
        __syncthreads();
        if (c >= off) {
            float4 p = lds[threadIdx.x - off * 2];
            v.x = fmaf(AP[s][0][0], p.x, fmaf(AP[s][0][1], p.y, fmaf(AP[s][0][2], p.z, fmaf(AP[s][0][3], p.w, v.x))));
            v.y = fmaf(AP[s][1][0], p.x, fmaf(AP[s][1][1], p.y, fmaf(AP[s][1][2], p.z, fmaf(AP[s][1][3], p.w, v.y))));
            v.z = fmaf(AP[s][2][0], p.x, fmaf(AP[s][2][1], p.y, fmaf(AP[s][2][2], p.z, fmaf(AP[s][2][3], p.w, v.z))));
            v.w = fmaf(AP[s][3][0], p.x, fmaf(AP[s][3][1], p.y, fmaf(AP[s][3][2], p.z, fmaf(AP[s][3][3], p.w, v.w))));
        }
        __syncthreads();
    }
    float4* ip = (float4*)ws_init;
    if (c < CH - 1) ip[(size_t)(c + 1) * NSEQ + seq] = v;
    if (c == 0)     ip[seq] = make_float4(0.f, 0.f, 0.f, 0.f);
}

__global__ __launch_bounds__(256) void k2_emit(
    const float* __restrict__ h, const float* __restrict__ ws_init,
    float* __restrict__ out)
{
    const int d = threadIdx.x;
    const int c = blockIdx.x & (CH - 1);
    const int b = blockIdx.x >> LOG_CH;

    float Af[4][4], Bf[4];
    base_consts(Af, Bf);

    float4 xi = ((const float4*)ws_init)[(size_t)c * NSEQ + b * D_ + d];
    float x0 = xi.x, x1 = xi.y, x2 = xi.z, x3 = xi.w;

    const float* hp = h + ((size_t)(b * T_ + c * L_)) * D_ + d;
    float* op = out + ((size_t)(b * T_ + c * L_)) * K_ * D_ + d;
#pragma unroll
    for (int i = 0; i < L_; ++i) {
        float hv = hp[i * D_];
        float n0 = fmaf(Af[0][0], x0, fmaf(Af[0][1], x1, fmaf(Af[0][2], x2, fmaf(Af[0][3], x3, Bf[0] * hv))));
        float n1 = fmaf(Af[1][0], x0, fmaf(Af[1][1], x1, fmaf(Af[1][2], x2, fmaf(Af[1][3], x3, Bf[1] * hv))));
        float n2 = fmaf(Af[2][0], x0, fmaf(Af[2][1], x1, fmaf(Af[2][2], x2, fmaf(Af[2][3], x3, Bf[2] * hv))));
        float n3 = fmaf(Af[3][0], x0, fmaf(Af[3][1], x1, fmaf(Af[3][2], x2, fmaf(Af[3][3], x3, Bf[3] * hv))));
        x0 = n0; x1 = n1; x2 = n2; x3 = n3;
        op[0 * D_] = x0; op[1 * D_] = x1; op[2 * D_] = x2; op[3 * D_] = x3;
        op += K_ * D_;
    }
}

} // namespace

extern "C" void kernel_launch(void* const* d_in, const int* in_sizes, int n_in,
                              void* d_out, int out_size, void* d_ws, size_t ws_size,
                              hipStream_t stream) {
    const float* h = (const float*)d_in[0];   // (B, T, D) fp32
    const float* M = (const float*)d_in[1];   // (T, K)    fp32
    float* out = (float*)d_out;               // (B, T, K, D) fp32

    // ws layout: y[CH][NSEQ][4] then init[CH][NSEQ][4]  (1 MiB each)
    float* ws_y    = (float*)d_ws;
    float* ws_init = ws_y + (size_t)CH * NSEQ * K_;

    void* args[] = {(void*)&h, (void*)&M, (void*)&ws_y, (void*)&ws_init, (void*)&out};
    hipError_t err = hipLaunchCooperativeKernel(
        (void*)fused_all, dim3(B_ * CH), dim3(256), args, 0, stream);

    if (err != hipSuccess) {
        // Fallback: original 3-kernel pipeline (never launch fused_all
        // non-cooperatively: its grid.sync() would hang).
        k1a_chunk_states<<<(NSEQ / 64) * (CH / 4), 256, 0, stream>>>(h, M, ws_y);
        k1b_scan<<<NSEQ / 2, 256, 0, stream>>>(ws_y, ws_init);
        k2_emit<<<B_ * CH, 256, 0, stream>>>(h, ws_init, out);
    }
}

// Round 2
// 81.124 us; speedup vs baseline: 2.0406x; 2.0406x over previous
//
#include <hip/hip_runtime.h>
#include <math.h>

namespace {

constexpr int K_ = 4;
constexpr int T_ = 1024;
constexpr int B_ = 2;
constexpr int D_ = 256;

constexpr int CH = 128;              // fine time chunks
constexpr int L_ = T_ / CH;          // 8 steps per chunk
constexpr int LOG_CH = 7;

// ---------------------------------------------------------------------------
// Compile-time-foldable constants: Abar, Bbar (bilinear LegT, N=4, theta=200)
// exactly as the reference builds them. All-double Gauss-Jordan, folded by
// the compiler to float literals (verified: VGPR_Count=16 in prior rounds).
// ---------------------------------------------------------------------------
__device__ __forceinline__ void base_consts(float Af[4][4], float Bf[4]) {
    const double dt = 1.0 / 200.0;
    double P[4], A[4][4];
#pragma unroll
    for (int n = 0; n < 4; ++n) P[n] = sqrt(2.0 * n + 1.0);
#pragma unroll
    for (int n = 0; n < 4; ++n)
#pragma unroll
        for (int k = 0; k < 4; ++k) {
            double s = (n >= k) ? 1.0 : (((k - n) & 1) ? -1.0 : 1.0);
            A[n][k] = -P[n] * P[k] * s;
        }
    double aug[4][9];
#pragma unroll
    for (int r = 0; r < 4; ++r) {
#pragma unroll
        for (int c = 0; c < 4; ++c) {
            double idc = (r == c) ? 1.0 : 0.0;
            aug[r][c]     = idc - 0.5 * dt * A[r][c];
            aug[r][4 + c] = idc + 0.5 * dt * A[r][c];
        }
        aug[r][8] = P[r] * dt;
    }
#pragma unroll
    for (int p = 0; p < 4; ++p) {
        double pinv = 1.0 / aug[p][p];
#pragma unroll
        for (int c = 0; c < 9; ++c) aug[p][c] *= pinv;
#pragma unroll
        for (int r = 0; r < 4; ++r) {
            if (r == p) continue;
            double f = aug[r][p];
#pragma unroll
            for (int c = 0; c < 9; ++c) aug[r][c] -= f * aug[p][c];
        }
    }
#pragma unroll
    for (int r = 0; r < 4; ++r) {
#pragma unroll
        for (int c = 0; c < 4; ++c) Af[r][c] = (float)aug[r][4 + c];
        Bf[r] = (float)aug[r][8];
    }
}

__device__ __forceinline__ void matsq(const float X[4][4], float Y[4][4]) {
#pragma unroll
    for (int r = 0; r < 4; ++r)
#pragma unroll
        for (int c = 0; c < 4; ++c) {
            float acc = 0.f;
#pragma unroll
            for (int k = 0; k < 4; ++k) acc = fmaf(X[r][k], X[k][c], acc);
            Y[r][c] = acc;
        }
}

// ===========================================================================
// Single fused kernel — no global sync, no workspace.
//
// Block (b,c), 512 threads = two 256-thread halves over d = tid & 255.
// The chunk recurrence is affine:  S_j = A8 * S_{j-1} + y_j,
//   y_j[d] = sum_{i<8} M[7-i] * h[b, 8j+i, d],   A8 = Abar^8 (const).
// Init state for chunk c is S_{c-1} = Horner over chunks 0..c-1.
//   half 0 computes Horner over chunks [0, c-64)        (<= 63 chunks)
//   half 1 computes Horner over chunks [max(c-64,0), c) (<= 64 chunks)
//   combine: S = A8^64 * S_half0 + S_half1   (A8^64 compile-time const;
//            when c < 64, S_half0 = 0 so the power is irrelevant)
// Then half 1 runs the 8-step emission for chunk c (same math as old k2).
//
// Work is uniform (<= 64 chunks per half) -> no tail-block straggler.
// h is 2 MiB -> L2-resident per XCD; the prefix re-reads are L2 traffic.
// ===========================================================================
__global__ __launch_bounds__(512) void hippo_fused(
    const float* __restrict__ h, const float* __restrict__ M,
    float* __restrict__ out)
{
    const int tid  = threadIdx.x;
    const int d    = tid & (D_ - 1);
    const int half = tid >> 8;               // 0 or 1
    const int c    = blockIdx.x & (CH - 1);
    const int b    = blockIdx.x >> LOG_CH;

    // ---- constants (all compile-time foldable) ----
    float Af[4][4], Bf[4];
    base_consts(Af, Bf);
    float P2[4][4], P4[4][4], A8[4][4];
    matsq(Af, P2);            // Abar^2
    matsq(P2, P4);            // Abar^4
    matsq(P4, A8);            // Abar^8
    float Q1[4][4], Q2[4][4];
    matsq(A8, Q1);            // A8^2
    matsq(Q1, Q2);            // A8^4
    matsq(Q2, Q1);            // A8^8
    matsq(Q1, Q2);            // A8^16
    matsq(Q2, Q1);            // A8^32
    matsq(Q1, Q2);            // Q2 = A8^64

    // ---- chunk-sum coefficients from global M (rows 0..7, uniform addr ->
    //      scalar loads). mcK[i] = M[7-i][K], matching old k1a numerics. ----
    float mc0[L_], mc1[L_], mc2[L_], mc3[L_];
#pragma unroll
    for (int i = 0; i < L_; ++i) {
        const float4 mr = ((const float4*)M)[L_ - 1 - i];
        mc0[i] = mr.x; mc1[i] = mr.y; mc2[i] = mr.z; mc3[i] = mr.w;
    }

    // ---- per-half Horner over chunk range ----
    const int cA = (c > 64) ? (c - 64) : 0;
    const int lo = half ? cA : 0;
    const int hi = half ? c  : cA;

    float x0 = 0.f, x1 = 0.f, x2 = 0.f, x3 = 0.f;
    const float* hp = h + ((size_t)(b * T_ + lo * L_)) * D_ + d;
    for (int j = lo; j < hi; ++j) {
        float y0 = 0.f, y1 = 0.f, y2 = 0.f, y3 = 0.f;
#pragma unroll
        for (int i = 0; i < L_; ++i) {
            float hv = hp[i * D_];            // 1 KiB coalesced per row
            y0 = fmaf(mc0[i], hv, y0);
            y1 = fmaf(mc1[i], hv, y1);
            y2 = fmaf(mc2[i], hv, y2);
            y3 = fmaf(mc3[i], hv, y3);
        }
        hp += L_ * D_;
        const float n0 = fmaf(A8[0][0], x0, fmaf(A8[0][1], x1, fmaf(A8[0][2], x2, fmaf(A8[0][3], x3, y0))));
        const float n1 = fmaf(A8[1][0], x0, fmaf(A8[1][1], x1, fmaf(A8[1][2], x2, fmaf(A8[1][3], x3, y1))));
        const float n2 = fmaf(A8[2][0], x0, fmaf(A8[2][1], x1, fmaf(A8[2][2], x2, fmaf(A8[2][3], x3, y2))));
        const float n3 = fmaf(A8[3][0], x0, fmaf(A8[3][1], x1, fmaf(A8[3][2], x2, fmaf(A8[3][3], x3, y3))));
        x0 = n0; x1 = n1; x2 = n2; x3 = n3;
    }

    // ---- combine halves: S = A8^64 * S_h0 + S_h1 ----
    __shared__ float xs[4][D_];
    if (half == 0) {
        xs[0][d] = x0; xs[1][d] = x1; xs[2][d] = x2; xs[3][d] = x3;
    }
    __syncthreads();

    if (half == 1) {
        const float a0 = xs[0][d], a1 = xs[1][d], a2 = xs[2][d], a3 = xs[3][d];
        x0 = fmaf(Q2[0][0], a0, fmaf(Q2[0][1], a1, fmaf(Q2[0][2], a2, fmaf(Q2[0][3], a3, x0))));
        x1 = fmaf(Q2[1][0], a0, fmaf(Q2[1][1], a1, fmaf(Q2[1][2], a2, fmaf(Q2[1][3], a3, x1))));
        x2 = fmaf(Q2[2][0], a0, fmaf(Q2[2][1], a1, fmaf(Q2[2][2], a2, fmaf(Q2[2][3], a3, x2))));
        x3 = fmaf(Q2[3][0], a0, fmaf(Q2[3][1], a1, fmaf(Q2[3][2], a2, fmaf(Q2[3][3], a3, x3))));

        // ---- emission for chunk c (identical math to old k2_emit) ----
        const float* hpe = h + ((size_t)(b * T_ + c * L_)) * D_ + d;
        float* op = out + ((size_t)(b * T_ + c * L_)) * K_ * D_ + d;
#pragma unroll
        for (int i = 0; i < L_; ++i) {
            const float hv = hpe[i * D_];
            const float n0 = fmaf(Af[0][0], x0, fmaf(Af[0][1], x1, fmaf(Af[0][2], x2, fmaf(Af[0][3], x3, Bf[0] * hv))));
            const float n1 = fmaf(Af[1][0], x0, fmaf(Af[1][1], x1, fmaf(Af[1][2], x2, fmaf(Af[1][3], x3, Bf[1] * hv))));
            const float n2 = fmaf(Af[2][0], x0, fmaf(Af[2][1], x1, fmaf(Af[2][2], x2, fmaf(Af[2][3], x3, Bf[2] * hv))));
            const float n3 = fmaf(Af[3][0], x0, fmaf(Af[3][1], x1, fmaf(Af[3][2], x2, fmaf(Af[3][3], x3, Bf[3] * hv))));
            x0 = n0; x1 = n1; x2 = n2; x3 = n3;
            op[0 * D_] = x0; op[1 * D_] = x1; op[2 * D_] = x2; op[3 * D_] = x3;
            op += K_ * D_;
        }
    }
}

} // namespace

extern "C" void kernel_launch(void* const* d_in, const int* in_sizes, int n_in,
                              void* d_out, int out_size, void* d_ws, size_t ws_size,
                              hipStream_t stream) {
    const float* h = (const float*)d_in[0];   // (B, T, D) fp32
    const float* M = (const float*)d_in[1];   // (T, K)    fp32
    float* out = (float*)d_out;               // (B, T, K, D) fp32
    (void)d_ws; (void)ws_size;                // workspace unused

    hippo_fused<<<B_ * CH, 512, 0, stream>>>(h, M, out);
}

// Round 3
// 72.643 us; speedup vs baseline: 2.2788x; 1.1167x over previous
//
#include <hip/hip_runtime.h>
#include <math.h>

namespace {

constexpr int K_ = 4;
constexpr int T_ = 1024;
constexpr int B_ = 2;
constexpr int D_ = 256;

constexpr int CH = 128;              // fine time chunks
constexpr int L_ = T_ / CH;          // 8 steps per chunk
constexpr int LOG_CH = 7;
constexpr int NW = 4;                // parallel prefix sub-ranges per block
constexpr int CPW = CH / NW;         // 32 chunks per sub-range

// ---------------------------------------------------------------------------
// Compile-time-foldable constants: Abar, Bbar (bilinear LegT, N=4, theta=200)
// exactly as the reference builds them. All-double Gauss-Jordan, folded by
// the compiler to float literals (verified: VGPR_Count=16 in earlier rounds).
// ---------------------------------------------------------------------------
__device__ __forceinline__ void base_consts(float Af[4][4], float Bf[4]) {
    const double dt = 1.0 / 200.0;
    double P[4], A[4][4];
#pragma unroll
    for (int n = 0; n < 4; ++n) P[n] = sqrt(2.0 * n + 1.0);
#pragma unroll
    for (int n = 0; n < 4; ++n)
#pragma unroll
        for (int k = 0; k < 4; ++k) {
            double s = (n >= k) ? 1.0 : (((k - n) & 1) ? -1.0 : 1.0);
            A[n][k] = -P[n] * P[k] * s;
        }
    double aug[4][9];
#pragma unroll
    for (int r = 0; r < 4; ++r) {
#pragma unroll
        for (int c = 0; c < 4; ++c) {
            double idc = (r == c) ? 1.0 : 0.0;
            aug[r][c]     = idc - 0.5 * dt * A[r][c];
            aug[r][4 + c] = idc + 0.5 * dt * A[r][c];
        }
        aug[r][8] = P[r] * dt;
    }
#pragma unroll
    for (int p = 0; p < 4; ++p) {
        double pinv = 1.0 / aug[p][p];
#pragma unroll
        for (int c = 0; c < 9; ++c) aug[p][c] *= pinv;
#pragma unroll
        for (int r = 0; r < 4; ++r) {
            if (r == p) continue;
            double f = aug[r][p];
#pragma unroll
            for (int c = 0; c < 9; ++c) aug[r][c] -= f * aug[p][c];
        }
    }
#pragma unroll
    for (int r = 0; r < 4; ++r) {
#pragma unroll
        for (int c = 0; c < 4; ++c) Af[r][c] = (float)aug[r][4 + c];
        Bf[r] = (float)aug[r][8];
    }
}

__device__ __forceinline__ void matsq(const float X[4][4], float Y[4][4]) {
#pragma unroll
    for (int r = 0; r < 4; ++r)
#pragma unroll
        for (int c = 0; c < 4; ++c) {
            float acc = 0.f;
#pragma unroll
            for (int k = 0; k < 4; ++k) acc = fmaf(X[r][k], X[k][c], acc);
            Y[r][c] = acc;
        }
}

// ===========================================================================
// Single kernel, no global sync, no workspace.
//
// Block (b,c) = blockIdx, 1024 threads: d = tid&255, w = tid>>8 (0..3).
// Chunk recurrence is affine: S_j = A8*S_{j-1} + y_j with A8 = Abar^8 const,
// y_j[d] = sum_{i<8} M[7-i]*h[8j+i,d].
//
// Prefix S_{c-1} split into NW=4 sub-ranges [w*32, min(w*32+32, c)):
//   P_w = Horner over the sub-range (<=32 serial iters, 1-deep manual
//         prefetch so the 8 loads of chunk j+1 are in flight during the
//         FMA chain of chunk j)
//   S   = sum_w A8^(c - hi_w) * P_w   (exponent block-uniform; applied as
//         16 FMAs per set bit using compile-time A8^(2^s) matrices)
// Combine via 16 KiB LDS, then wave-group 0 emits chunk c's 8 timesteps
// (same math as the verified k2_emit), with nontemporal stores so the
// 8 MiB output stream does not evict L2-resident h.
// ===========================================================================
__global__ __launch_bounds__(1024) void hippo_one(
    const float* __restrict__ h, const float* __restrict__ M,
    float* __restrict__ out)
{
    const int tid = threadIdx.x;
    const int d   = tid & (D_ - 1);
    const int w   = tid >> 8;               // 0..3
    const int c   = blockIdx.x & (CH - 1);
    const int b   = blockIdx.x >> LOG_CH;

    // ---- constants (compile-time foldable) ----
    float Af[4][4], Bf[4];
    base_consts(Af, Bf);
    float T2[4][4], T4[4][4];
    float A8p[LOG_CH][4][4];                // A8p[s] = (Abar^8)^(2^s)
    matsq(Af, T2);                          // Abar^2
    matsq(T2, T4);                          // Abar^4
    matsq(T4, A8p[0]);                      // Abar^8
#pragma unroll
    for (int s = 1; s < LOG_CH; ++s) matsq(A8p[s - 1], A8p[s]);

    // ---- chunk-sum coefficients mc[i][k] = M[7-i][k] (uniform loads) ----
    float mc[L_][K_];
#pragma unroll
    for (int i = 0; i < L_; ++i) {
        const float4 mr = ((const float4*)M)[L_ - 1 - i];
        mc[i][0] = mr.x; mc[i][1] = mr.y; mc[i][2] = mr.z; mc[i][3] = mr.w;
    }

    // ---- sub-range Horner with 1-deep load pipeline ----
    const int lo = w * CPW;
    const int hi = (c < lo + CPW) ? c : (lo + CPW);   // empty if lo >= c

    const float* hb = h + (size_t)b * (T_ * D_) + d;

    float x0 = 0.f, x1 = 0.f, x2 = 0.f, x3 = 0.f;
    float a0 = 0.f, a1 = 0.f, a2 = 0.f, a3 = 0.f,
          a4 = 0.f, a5 = 0.f, a6 = 0.f, a7 = 0.f;
    float p0 = 0.f, p1 = 0.f, p2 = 0.f, p3 = 0.f,
          p4 = 0.f, p5 = 0.f, p6 = 0.f, p7 = 0.f;

    if (lo < hi) {
        const float* q = hb + (size_t)lo * (L_ * D_);
        a0 = q[0 * D_]; a1 = q[1 * D_]; a2 = q[2 * D_]; a3 = q[3 * D_];
        a4 = q[4 * D_]; a5 = q[5 * D_]; a6 = q[6 * D_]; a7 = q[7 * D_];
    }
    for (int j = lo; j < hi; ++j) {
        if (j + 1 < hi) {                   // issue next chunk's loads early
            const float* q = hb + (size_t)(j + 1) * (L_ * D_);
            p0 = q[0 * D_]; p1 = q[1 * D_]; p2 = q[2 * D_]; p3 = q[3 * D_];
            p4 = q[4 * D_]; p5 = q[5 * D_]; p6 = q[6 * D_]; p7 = q[7 * D_];
        }
        float y0 = mc[0][0] * a0, y1 = mc[0][1] * a0,
              y2 = mc[0][2] * a0, y3 = mc[0][3] * a0;
        y0 = fmaf(mc[1][0], a1, y0); y1 = fmaf(mc[1][1], a1, y1);
        y2 = fmaf(mc[1][2], a1, y2); y3 = fmaf(mc[1][3], a1, y3);
        y0 = fmaf(mc[2][0], a2, y0); y1 = fmaf(mc[2][1], a2, y1);
        y2 = fmaf(mc[2][2], a2, y2); y3 = fmaf(mc[2][3], a2, y3);
        y0 = fmaf(mc[3][0], a3, y0); y1 = fmaf(mc[3][1], a3, y1);
        y2 = fmaf(mc[3][2], a3, y2); y3 = fmaf(mc[3][3], a3, y3);
        y0 = fmaf(mc[4][0], a4, y0); y1 = fmaf(mc[4][1], a4, y1);
        y2 = fmaf(mc[4][2], a4, y2); y3 = fmaf(mc[4][3], a4, y3);
        y0 = fmaf(mc[5][0], a5, y0); y1 = fmaf(mc[5][1], a5, y1);
        y2 = fmaf(mc[5][2], a5, y2); y3 = fmaf(mc[5][3], a5, y3);
        y0 = fmaf(mc[6][0], a6, y0); y1 = fmaf(mc[6][1], a6, y1);
        y2 = fmaf(mc[6][2], a6, y2); y3 = fmaf(mc[6][3], a6, y3);
        y0 = fmaf(mc[7][0], a7, y0); y1 = fmaf(mc[7][1], a7, y1);
        y2 = fmaf(mc[7][2], a7, y2); y3 = fmaf(mc[7][3], a7, y3);

        const float n0 = fmaf(A8p[0][0][0], x0, fmaf(A8p[0][0][1], x1, fmaf(A8p[0][0][2], x2, fmaf(A8p[0][0][3], x3, y0))));
        const float n1 = fmaf(A8p[0][1][0], x0, fmaf(A8p[0][1][1], x1, fmaf(A8p[0][1][2], x2, fmaf(A8p[0][1][3], x3, y1))));
        const float n2 = fmaf(A8p[0][2][0], x0, fmaf(A8p[0][2][1], x1, fmaf(A8p[0][2][2], x2, fmaf(A8p[0][2][3], x3, y2))));
        const float n3 = fmaf(A8p[0][3][0], x0, fmaf(A8p[0][3][1], x1, fmaf(A8p[0][3][2], x2, fmaf(A8p[0][3][3], x3, y3))));
        x0 = n0; x1 = n1; x2 = n2; x3 = n3;

        a0 = p0; a1 = p1; a2 = p2; a3 = p3;
        a4 = p4; a5 = p5; a6 = p6; a7 = p7;
    }

    // ---- scale partial by A8^(c - hi): per-bit constant-matrix applies ----
    const int kexp = c - hi;                // 0..95, block-uniform
#pragma unroll
    for (int s = 0; s < LOG_CH; ++s) {
        if ((kexp >> s) & 1) {
            const float t0 = fmaf(A8p[s][0][0], x0, fmaf(A8p[s][0][1], x1, fmaf(A8p[s][0][2], x2, A8p[s][0][3] * x3)));
            const float t1 = fmaf(A8p[s][1][0], x0, fmaf(A8p[s][1][1], x1, fmaf(A8p[s][1][2], x2, A8p[s][1][3] * x3)));
            const float t2 = fmaf(A8p[s][2][0], x0, fmaf(A8p[s][2][1], x1, fmaf(A8p[s][2][2], x2, A8p[s][2][3] * x3)));
            const float t3 = fmaf(A8p[s][3][0], x0, fmaf(A8p[s][3][1], x1, fmaf(A8p[s][3][2], x2, A8p[s][3][3] * x3)));
            x0 = t0; x1 = t1; x2 = t2; x3 = t3;
        }
    }

    // ---- combine the 4 partials via LDS ----
    __shared__ float xs[NW][K_][D_];        // 16 KiB
    xs[w][0][d] = x0; xs[w][1][d] = x1; xs[w][2][d] = x2; xs[w][3][d] = x3;
    __syncthreads();

    if (w == 0) {
        float s0 = (xs[0][0][d] + xs[1][0][d]) + (xs[2][0][d] + xs[3][0][d]);
        float s1 = (xs[0][1][d] + xs[1][1][d]) + (xs[2][1][d] + xs[3][1][d]);
        float s2 = (xs[0][2][d] + xs[1][2][d]) + (xs[2][2][d] + xs[3][2][d]);
        float s3 = (xs[0][3][d] + xs[1][3][d]) + (xs[2][3][d] + xs[3][3][d]);

        // ---- emission for chunk c (identical math to verified k2_emit) ----
        const float* hpe = hb + (size_t)c * (L_ * D_);
        float* op = out + ((size_t)(b * T_ + c * L_)) * (K_ * D_) + d;
#pragma unroll
        for (int i = 0; i < L_; ++i) {
            const float hv = hpe[i * D_];
            const float n0 = fmaf(Af[0][0], s0, fmaf(Af[0][1], s1, fmaf(Af[0][2], s2, fmaf(Af[0][3], s3, Bf[0] * hv))));
            const float n1 = fmaf(Af[1][0], s0, fmaf(Af[1][1], s1, fmaf(Af[1][2], s2, fmaf(Af[1][3], s3, Bf[1] * hv))));
            const float n2 = fmaf(Af[2][0], s0, fmaf(Af[2][1], s1, fmaf(Af[2][2], s2, fmaf(Af[2][3], s3, Bf[2] * hv))));
            const float n3 = fmaf(Af[3][0], s0, fmaf(Af[3][1], s1, fmaf(Af[3][2], s2, fmaf(Af[3][3], s3, Bf[3] * hv))));
            s0 = n0; s1 = n1; s2 = n2; s3 = n3;
            __builtin_nontemporal_store(s0, &op[0 * D_]);
            __builtin_nontemporal_store(s1, &op[1 * D_]);
            __builtin_nontemporal_store(s2, &op[2 * D_]);
            __builtin_nontemporal_store(s3, &op[3 * D_]);
            op += K_ * D_;
        }
    }
}

} // namespace

extern "C" void kernel_launch(void* const* d_in, const int* in_sizes, int n_in,
                              void* d_out, int out_size, void* d_ws, size_t ws_size,
                              hipStream_t stream) {
    const float* h = (const float*)d_in[0];   // (B, T, D) fp32
    const float* M = (const float*)d_in[1];   // (T, K)    fp32
    float* out = (float*)d_out;               // (B, T, K, D) fp32
    (void)d_ws; (void)ws_size;                // workspace unused

    hippo_one<<<B_ * CH, 1024, 0, stream>>>(h, M, out);
}